// Round 7
// baseline (145.093 us; speedup 1.0000x reference)
//
#include <hip/hip_runtime.h>
#include <hip/hip_fp16.h>
#include <stdint.h>

#define NH 32   // heads (fixed by table shapes)

__device__ __forceinline__ float bf_to_f(uint16_t u)
{
    return __uint_as_float(((uint32_t)u) << 16);
}

// Block-wide dtype sniff on first 4096 B of spd_table. bf16 N(0,1) never has
// exp field >= 0x89; fp32 low halves do with prob ~1. Returns 1 if fp32.
// (Consistently detected fp32 on this bench.)
__device__ __forceinline__ int block_detect_fp32(const uint16_t* p16, int tid,
                                                 int* s_flag)
{
    if (tid == 0) *s_flag = 0;
    __syncthreads();
    const ushort4* p = (const ushort4*)p16;
    ushort4 a = p[tid * 2];
    ushort4 b = p[tid * 2 + 1];
    int big = 0;
    big |= (((a.x >> 7) & 0xFF) >= 0x89); big |= (((a.y >> 7) & 0xFF) >= 0x89);
    big |= (((a.z >> 7) & 0xFF) >= 0x89); big |= (((a.w >> 7) & 0xFF) >= 0x89);
    big |= (((b.x >> 7) & 0xFF) >= 0x89); big |= (((b.y >> 7) & 0xFF) >= 0x89);
    big |= (((b.z >> 7) & 0xFF) >= 0x89); big |= (((b.w >> 7) & 0xFF) >= 0x89);
    if (big) atomicOr(s_flag, 1);
    __syncthreads();
    return *s_flag;
}

// ---------------------------------------------------------------------------
// Fused prep: threads [0,totalT) build T16[d][e][k] = fp16(sum_h et[e][h]*W[d,h,k])
// (fp32 accumulate, one RN round to fp16 at the end); threads [totalT, +spd_n)
// convert spd_table to fp32.
// ---------------------------------------------------------------------------
__global__ __launch_bounds__(256) void prep(
    const void* __restrict__ edge_table,
    const void* __restrict__ W,
    const void* __restrict__ spd,
    __half* __restrict__ T16,
    float* __restrict__ spdf,
    int totalT, int spd_n)
{
    __shared__ int s_flag;
    const int tid = threadIdx.x;
    const int is_fp32 = block_detect_fp32((const uint16_t*)spd, tid, &s_flag);
    int g = blockIdx.x * 256 + tid;
    if (g < totalT) {
        int d = g >> 10, e = (g >> 5) & 31, k = g & 31;
        float acc = 0.f;
        if (is_fp32) {
            const float* et = (const float*)edge_table + e * NH;
            const float* w  = (const float*)W + d * NH * NH + k;
#pragma unroll
            for (int h = 0; h < NH; ++h) acc += et[h] * w[h * NH];
        } else {
            const uint16_t* et = (const uint16_t*)edge_table + e * NH;
            const uint16_t* w  = (const uint16_t*)W + d * NH * NH + k;
#pragma unroll
            for (int h = 0; h < NH; ++h) acc += bf_to_f(et[h]) * bf_to_f(w[h * NH]);
        }
        T16[g] = __float2half(acc);
    } else {
        int i = g - totalT;
        if (i < spd_n)
            spdf[i] = is_fp32 ? ((const float*)spd)[i]
                              : bf_to_f(((const uint16_t*)spd)[i]);
    }
}

__device__ __forceinline__ void acc8(float* acc, uint4 v)
{
    const __half2* h = (const __half2*)&v;
    float2 f0 = __half22float2(h[0]);
    float2 f1 = __half22float2(h[1]);
    float2 f2 = __half22float2(h[2]);
    float2 f3 = __half22float2(h[3]);
    acc[0] += f0.x; acc[1] += f0.y; acc[2] += f1.x; acc[3] += f1.y;
    acc[4] += f2.x; acc[5] += f2.y; acc[6] += f3.x; acc[7] += f3.y;
}

// ---------------------------------------------------------------------------
// Main kernel. FP32 output:
//   out[h*npairs + p]             = spd_table[s_p, h]            (phi_spd)
//   out[32*npairs + k*npairs + p] = (sum_d T[d,e_pd,k]) / s~_p   (phi_edge)
// T held in LDS as fp16: 32 KiB per 16-d chunk -> per-pair row = 64 B = 4
// ds_read_b128 per d (half the LDS traffic of fp32 — LDS pipe is the floor).
// Swizzle: 2 e-rows share a 128-B window; chunk slot w' = ((e&1)*4+m) ^
// ((e>>1)&7) is uniform over the 8 bank groups for random e, and XOR-linear
// in m so reads are boff ^ (m<<4). fp32 accumulation; plain (cached) stores —
// nt stores regressed (R6): dirty output lines get re-poisoned in L2/L3
// without draining to HBM.
// ---------------------------------------------------------------------------
__global__ __launch_bounds__(256, 2) void bond2d(
    const int* __restrict__ spatial,
    const int* __restrict__ edge,
    const float* __restrict__ spd_f32,
    const uint4* __restrict__ Tg16,         // D*128 16B-chunks of fp16 T
    float* __restrict__ out,
    int npairs, int D)
{
    __shared__ uint4 Tl[2048];                   // 32768 B per 16-d chunk

    const int t     = threadIdx.x;
    const int pw    = blockIdx.x * 256 + t;      // pair-duo index
    const int base0 = 2 * pw;
    const bool valid = (base0 + 1 < npairs);
    const int base  = valid ? base0 : 0;

    int2 ss = *(const int2*)(spatial + base);

    float acc0[32], acc1[32];
#pragma unroll
    for (int k = 0; k < 32; ++k) { acc0[k] = 0.f; acc1[k] = 0.f; }

    for (int c0 = 0; c0 < D; c0 += 16) {
        const int dlen = (D - c0 < 16) ? (D - c0) : 16;
        const int nch  = dlen * 128;             // 16B chunks this pass
        __syncthreads();                         // prior pass reads complete
        // stage: chunk q -> (d = q>>7, e = (q>>2)&31, m = q&3)
        // phys byte = (d<<11) + ((e>>1)<<7) + ((((e&1)<<2)|m) ^ ((e>>1)&7))<<4
        if (dlen == 16) {
#pragma unroll
            for (int i = 0; i < 8; ++i) {
                int q = t + i * 256;
                uint4 v = Tg16[c0 * 128 + q];
                int d = q >> 7, e = (q >> 2) & 31, m = q & 3;
                int slot = (d << 11) + ((e >> 1) << 7)
                         + (((((e & 1) << 2) | m) ^ ((e >> 1) & 7)) << 4);
                *(uint4*)((char*)Tl + slot) = v;
            }
        } else {
            for (int q = t; q < nch; q += 256) {
                uint4 v = Tg16[c0 * 128 + q];
                int d = q >> 7, e = (q >> 2) & 31, m = q & 3;
                int slot = (d << 11) + ((e >> 1) << 7)
                         + (((((e & 1) << 2) | m) ^ ((e >> 1) & 7)) << 4);
                *(uint4*)((char*)Tl + slot) = v;
            }
        }
        const int* r0 = edge + (size_t)(base + 0) * D + c0;
        const int* r1 = edge + (size_t)(base + 1) * D + c0;

        if (dlen == 16) {
            int4 q0 = ((const int4*)r0)[0], q1 = ((const int4*)r0)[1];
            int4 q2 = ((const int4*)r0)[2], q3 = ((const int4*)r0)[3];
            int4 q4 = ((const int4*)r1)[0], q5 = ((const int4*)r1)[1];
            int4 q6 = ((const int4*)r1)[2], q7 = ((const int4*)r1)[3];
            int e0[16], e1[16];
            e0[0]=q0.x; e0[1]=q0.y; e0[2]=q0.z; e0[3]=q0.w;
            e0[4]=q1.x; e0[5]=q1.y; e0[6]=q1.z; e0[7]=q1.w;
            e0[8]=q2.x; e0[9]=q2.y; e0[10]=q2.z; e0[11]=q2.w;
            e0[12]=q3.x; e0[13]=q3.y; e0[14]=q3.z; e0[15]=q3.w;
            e1[0]=q4.x; e1[1]=q4.y; e1[2]=q4.z; e1[3]=q4.w;
            e1[4]=q5.x; e1[5]=q5.y; e1[6]=q5.z; e1[7]=q5.w;
            e1[8]=q6.x; e1[9]=q6.y; e1[10]=q6.z; e1[11]=q6.w;
            e1[12]=q7.x; e1[13]=q7.y; e1[14]=q7.z; e1[15]=q7.w;
            __syncthreads();
#pragma unroll
            for (int d = 0; d < 16; ++d) {
                {
                    int e = e0[d];
                    int boff = (d << 11) + ((e >> 1) << 7)
                             + ((((e & 1) << 2) ^ ((e >> 1) & 7)) << 4);
#pragma unroll
                    for (int m = 0; m < 4; ++m) {
                        uint4 v = *(const uint4*)((const char*)Tl + (boff ^ (m << 4)));
                        acc8(&acc0[8 * m], v);
                    }
                }
                {
                    int e = e1[d];
                    int boff = (d << 11) + ((e >> 1) << 7)
                             + ((((e & 1) << 2) ^ ((e >> 1) & 7)) << 4);
#pragma unroll
                    for (int m = 0; m < 4; ++m) {
                        uint4 v = *(const uint4*)((const char*)Tl + (boff ^ (m << 4)));
                        acc8(&acc1[8 * m], v);
                    }
                }
            }
        } else {
            int e0[16], e1[16];
            for (int d = 0; d < dlen; ++d) { e0[d] = r0[d]; e1[d] = r1[d]; }
            __syncthreads();
            for (int d = 0; d < dlen; ++d) {
                {
                    int e = e0[d];
                    int boff = (d << 11) + ((e >> 1) << 7)
                             + ((((e & 1) << 2) ^ ((e >> 1) & 7)) << 4);
#pragma unroll
                    for (int m = 0; m < 4; ++m) {
                        uint4 v = *(const uint4*)((const char*)Tl + (boff ^ (m << 4)));
                        acc8(&acc0[8 * m], v);
                    }
                }
                {
                    int e = e1[d];
                    int boff = (d << 11) + ((e >> 1) << 7)
                             + ((((e & 1) << 2) ^ ((e >> 1) & 7)) << 4);
#pragma unroll
                    for (int m = 0; m < 4; ++m) {
                        uint4 v = *(const uint4*)((const char*)Tl + (boff ^ (m << 4)));
                        acc8(&acc1[8 * m], v);
                    }
                }
            }
        }
    }

    if (!valid) return;

    // ---- phi_edge: plain float2 stores ----
    float r0f = 1.0f / (ss.x ? (float)ss.x : 1.0f);
    float r1f = 1.0f / (ss.y ? (float)ss.y : 1.0f);
    float* o1 = out + (size_t)NH * npairs;
#pragma unroll
    for (int k = 0; k < 32; ++k)
        *(float2*)(o1 + (size_t)k * npairs + base0) =
            make_float2(acc0[k] * r0f, acc1[k] * r1f);

    // ---- phi_spd: fp32 gather (L1-hot) + float2 stores ----
    const float* rA = spd_f32 + ss.x * NH;
    const float* rB = spd_f32 + ss.y * NH;
#pragma unroll
    for (int h = 0; h < 32; ++h)
        *(float2*)(out + (size_t)h * npairs + base0) =
            make_float2(rA[h], rB[h]);
}

extern "C" void kernel_launch(void* const* d_in, const int* in_sizes, int n_in,
                              void* d_out, int out_size, void* d_ws, size_t ws_size,
                              hipStream_t stream) {
    // dict order: [0]=spatial_pos [1]=edge_input [2]=max_dist [3]=spd_table
    //             [4]=edge_table  [5]=edge_dis_weight
    const int* spatial = (const int*)d_in[0];
    const int* edge    = (const int*)d_in[1];
    const void* spd    = d_in[3];
    const void* etab   = d_in[4];
    const void* W      = d_in[5];

    long long npairs = in_sizes[0];
    long long etot   = in_sizes[1];
    int D = (int)(etot / (npairs > 0 ? npairs : 1));
    if (D < 1) D = 1;
    if (D > 64) D = 64;
    int spd_n  = in_sizes[3];
    int totalT = D * 1024;

    __half* T16 = (__half*)d_ws;                  // D*1024 fp16 (<=128 KB)
    float*  spdf = (float*)((char*)d_ws + ((size_t)totalT * 2 + 255 & ~255ull));

    prep<<<(totalT + spd_n + 255) / 256, 256, 0, stream>>>(
        etab, W, spd, T16, spdf, totalT, spd_n);

    int nblk = (int)((npairs + 511) / 512);
    bond2d<<<nblk, 256, 0, stream>>>(spatial, edge, spdf, (const uint4*)T16,
                                     (float*)d_out, (int)npairs, D);
}

// Round 8
// 119.301 us; speedup vs baseline: 1.2162x; 1.2162x over previous
//
#include <hip/hip_runtime.h>
#include <stdint.h>

#define NH 32   // heads (fixed by table shapes)

__device__ __forceinline__ float bf_to_f(uint16_t u)
{
    return __uint_as_float(((uint32_t)u) << 16);
}

// Block-wide dtype sniff on first 4096 B of spd_table. bf16 N(0,1) never has
// exp field >= 0x89; fp32 low halves do with prob ~1. Returns 1 if fp32.
// (Consistently detected fp32 on this bench.)
__device__ __forceinline__ int block_detect_fp32(const uint16_t* p16, int tid,
                                                 int* s_flag)
{
    if (tid == 0) *s_flag = 0;
    __syncthreads();
    const ushort4* p = (const ushort4*)p16;
    ushort4 a = p[tid * 2];
    ushort4 b = p[tid * 2 + 1];
    int big = 0;
    big |= (((a.x >> 7) & 0xFF) >= 0x89); big |= (((a.y >> 7) & 0xFF) >= 0x89);
    big |= (((a.z >> 7) & 0xFF) >= 0x89); big |= (((a.w >> 7) & 0xFF) >= 0x89);
    big |= (((b.x >> 7) & 0xFF) >= 0x89); big |= (((b.y >> 7) & 0xFF) >= 0x89);
    big |= (((b.z >> 7) & 0xFF) >= 0x89); big |= (((b.w >> 7) & 0xFF) >= 0x89);
    if (big) atomicOr(s_flag, 1);
    __syncthreads();
    return *s_flag;
}

// ---------------------------------------------------------------------------
// Fused prep: threads [0, totalT) build T[d][e][k] = sum_h etab[e][h]*W[d,h,k]
// in fp32; threads [totalT, totalT+spd_n) convert spd_table to fp32.
// ---------------------------------------------------------------------------
__global__ __launch_bounds__(256) void prep(
    const void* __restrict__ edge_table,
    const void* __restrict__ W,
    const void* __restrict__ spd,
    float* __restrict__ T,
    float* __restrict__ spdf,
    int totalT, int spd_n)
{
    __shared__ int s_flag;
    const int tid = threadIdx.x;
    const int is_fp32 = block_detect_fp32((const uint16_t*)spd, tid, &s_flag);
    int g = blockIdx.x * 256 + tid;
    if (g < totalT) {
        int d = g >> 10, e = (g >> 5) & 31, k = g & 31;
        float acc = 0.f;
        if (is_fp32) {
            const float* et = (const float*)edge_table + e * NH;
            const float* w  = (const float*)W + d * NH * NH + k;
#pragma unroll
            for (int h = 0; h < NH; ++h) acc += et[h] * w[h * NH];
        } else {
            const uint16_t* et = (const uint16_t*)edge_table + e * NH;
            const uint16_t* w  = (const uint16_t*)W + d * NH * NH + k;
#pragma unroll
            for (int h = 0; h < NH; ++h) acc += bf_to_f(et[h]) * bf_to_f(w[h * NH]);
        }
        T[g] = acc;
    } else {
        int i = g - totalT;
        if (i < spd_n)
            spdf[i] = is_fp32 ? ((const float*)spd)[i]
                              : bf_to_f(((const uint16_t*)spd)[i]);
    }
}

// ---------------------------------------------------------------------------
// Main kernel (R5 structure — best measured: bond2d <= 43.7 us in-kernel).
// FP32 output:
//   out[h*npairs + p]             = spd_table[s_p, h]            (phi_spd)
//   out[32*npairs + k*npairs + p] = (sum_d T[d,e_pd,k]) / s~_p   (phi_edge)
// T in fp32 in 64 KiB LDS (16-d chunk), 16 B chunks XOR-swizzled by e&7
// (2-way max aliasing for random e -> conflict-free per m136).
// Plain cached stores: deferred L2/L3 drain overlaps the next harness fill
// (R6: nt stores neutral-to-worse; R7: fp16 LDS regressed — lost latency
// hiding on HBM edge loads. Iteration is globally HBM-traffic-bound.)
// ---------------------------------------------------------------------------
__global__ __launch_bounds__(256, 2) void bond2d(
    const int* __restrict__ spatial,
    const int* __restrict__ edge,
    const float* __restrict__ spd_f32,
    const float4* __restrict__ Tg,
    float* __restrict__ out,
    int npairs, int D)
{
    __shared__ float4 Tl[4096];                  // 65536 B

    const int t     = threadIdx.x;
    const int pw    = blockIdx.x * 256 + t;      // pair-duo index
    const int base0 = 2 * pw;
    const bool valid = (base0 + 1 < npairs);
    const int base  = valid ? base0 : 0;

    int2 ss = *(const int2*)(spatial + base);

    float acc0[32], acc1[32];
#pragma unroll
    for (int k = 0; k < 32; ++k) { acc0[k] = 0.f; acc1[k] = 0.f; }

    for (int c0 = 0; c0 < D; c0 += 16) {
        const int dlen = (D - c0 < 16) ? (D - c0) : 16;
        __syncthreads();                         // prior pass reads complete
        if (dlen == 16) {
#pragma unroll
            for (int i = 0; i < 16; ++i) {
                int q = t + i * 256;
                float4 v = Tg[c0 * 256 + q];
                int e    = (q >> 3) & 31;
                int slot = (q & ~7) | ((q & 7) ^ (e & 7));
                Tl[slot] = v;
            }
        } else {
            for (int i = t; i < dlen * 256; i += 256) {
                float4 v = Tg[c0 * 256 + i];
                int e    = (i >> 3) & 31;
                int slot = (i & ~7) | ((i & 7) ^ (e & 7));
                Tl[slot] = v;
            }
        }
        const int* r0 = edge + (size_t)(base + 0) * D + c0;
        const int* r1 = edge + (size_t)(base + 1) * D + c0;

        if (dlen == 16) {
            int4 q0 = ((const int4*)r0)[0], q1 = ((const int4*)r0)[1];
            int4 q2 = ((const int4*)r0)[2], q3 = ((const int4*)r0)[3];
            int4 q4 = ((const int4*)r1)[0], q5 = ((const int4*)r1)[1];
            int4 q6 = ((const int4*)r1)[2], q7 = ((const int4*)r1)[3];
            int e0[16], e1[16];
            e0[0]=q0.x; e0[1]=q0.y; e0[2]=q0.z; e0[3]=q0.w;
            e0[4]=q1.x; e0[5]=q1.y; e0[6]=q1.z; e0[7]=q1.w;
            e0[8]=q2.x; e0[9]=q2.y; e0[10]=q2.z; e0[11]=q2.w;
            e0[12]=q3.x; e0[13]=q3.y; e0[14]=q3.z; e0[15]=q3.w;
            e1[0]=q4.x; e1[1]=q4.y; e1[2]=q4.z; e1[3]=q4.w;
            e1[4]=q5.x; e1[5]=q5.y; e1[6]=q5.z; e1[7]=q5.w;
            e1[8]=q6.x; e1[9]=q6.y; e1[10]=q6.z; e1[11]=q6.w;
            e1[12]=q7.x; e1[13]=q7.y; e1[14]=q7.z; e1[15]=q7.w;
            __syncthreads();
#pragma unroll
            for (int d = 0; d < 16; ++d) {
                {
                    int e = e0[d];
                    int boff = (d << 12) + (e << 7) + ((e & 7) << 4);
#pragma unroll
                    for (int m = 0; m < 8; ++m) {
                        float4 v = *(const float4*)((const char*)Tl + (boff ^ (m << 4)));
                        acc0[4*m+0] += v.x; acc0[4*m+1] += v.y;
                        acc0[4*m+2] += v.z; acc0[4*m+3] += v.w;
                    }
                }
                {
                    int e = e1[d];
                    int boff = (d << 12) + (e << 7) + ((e & 7) << 4);
#pragma unroll
                    for (int m = 0; m < 8; ++m) {
                        float4 v = *(const float4*)((const char*)Tl + (boff ^ (m << 4)));
                        acc1[4*m+0] += v.x; acc1[4*m+1] += v.y;
                        acc1[4*m+2] += v.z; acc1[4*m+3] += v.w;
                    }
                }
            }
        } else {
            int e0[16], e1[16];
            for (int d = 0; d < dlen; ++d) { e0[d] = r0[d]; e1[d] = r1[d]; }
            __syncthreads();
            for (int d = 0; d < dlen; ++d) {
                {
                    int e = e0[d];
                    int boff = (d << 12) + (e << 7) + ((e & 7) << 4);
#pragma unroll
                    for (int m = 0; m < 8; ++m) {
                        float4 v = *(const float4*)((const char*)Tl + (boff ^ (m << 4)));
                        acc0[4*m+0] += v.x; acc0[4*m+1] += v.y;
                        acc0[4*m+2] += v.z; acc0[4*m+3] += v.w;
                    }
                }
                {
                    int e = e1[d];
                    int boff = (d << 12) + (e << 7) + ((e & 7) << 4);
#pragma unroll
                    for (int m = 0; m < 8; ++m) {
                        float4 v = *(const float4*)((const char*)Tl + (boff ^ (m << 4)));
                        acc1[4*m+0] += v.x; acc1[4*m+1] += v.y;
                        acc1[4*m+2] += v.z; acc1[4*m+3] += v.w;
                    }
                }
            }
        }
    }

    if (!valid) return;

    // ---- phi_edge: plain float2 stores ----
    float r0f = 1.0f / (ss.x ? (float)ss.x : 1.0f);
    float r1f = 1.0f / (ss.y ? (float)ss.y : 1.0f);
    float* o1 = out + (size_t)NH * npairs;
#pragma unroll
    for (int k = 0; k < 32; ++k)
        *(float2*)(o1 + (size_t)k * npairs + base0) =
            make_float2(acc0[k] * r0f, acc1[k] * r1f);

    // ---- phi_spd: fp32 gather (L1-hot) + float2 stores ----
    const float* rA = spd_f32 + ss.x * NH;
    const float* rB = spd_f32 + ss.y * NH;
#pragma unroll
    for (int h = 0; h < 32; ++h)
        *(float2*)(out + (size_t)h * npairs + base0) =
            make_float2(rA[h], rB[h]);
}

extern "C" void kernel_launch(void* const* d_in, const int* in_sizes, int n_in,
                              void* d_out, int out_size, void* d_ws, size_t ws_size,
                              hipStream_t stream) {
    // dict order: [0]=spatial_pos [1]=edge_input [2]=max_dist [3]=spd_table
    //             [4]=edge_table  [5]=edge_dis_weight
    const int* spatial = (const int*)d_in[0];
    const int* edge    = (const int*)d_in[1];
    const void* spd    = d_in[3];
    const void* etab   = d_in[4];
    const void* W      = d_in[5];

    long long npairs = in_sizes[0];
    long long etot   = in_sizes[1];
    int D = (int)(etot / (npairs > 0 ? npairs : 1));
    if (D < 1) D = 1;
    if (D > 64) D = 64;
    int spd_n  = in_sizes[3];
    int totalT = D * 1024;

    float* T    = (float*)d_ws;                   // D*1024 fp32
    float* spdf = T + totalT;

    prep<<<(totalT + spd_n + 255) / 256, 256, 0, stream>>>(
        etab, W, spd, T, spdf, totalT, spd_n);

    int nblk = (int)((npairs + 511) / 512);
    bond2d<<<nblk, 256, 0, stream>>>(spatial, edge, spdf, (const float4*)T,
                                     (float*)d_out, (int)npairs, D);
}